// Round 2
// baseline (1117.890 us; speedup 1.0000x reference)
//
#include <hip/hip_runtime.h>
#include <hip/hip_bf16.h>

// Shapes
#define NG 16
#define NN 2048
#define NF 32
#define NE 32768
#define IND 65536   // NN*NF
#define HD 512
#define LD 64

typedef unsigned int u32;

// ---------------- GCN part ----------------

// xw = x @ W_gcn   (per flat node)
__global__ void k_xw(const float* __restrict__ x, const float* __restrict__ Wg,
                     float* __restrict__ xw){
  __shared__ float ws[32][33];
  __shared__ float xsh[8][32];
  int t = threadIdx.x;
  for (int i = t; i < 1024; i += 256) ws[i >> 5][i & 31] = Wg[i];
  int base = blockIdx.x * 8;            // flat node index (g*NN+n)
  int r = t >> 5, f = t & 31;
  xsh[r][f] = x[(base + r) * 32 + f];
  __syncthreads();
  float acc = 0.f;
  #pragma unroll
  for (int k = 0; k < 32; ++k) acc += xsh[r][k] * ws[k][f];
  xw[(base + r) * 32 + f] = acc;
}

__global__ void k_deg(const int* __restrict__ ei, u32* __restrict__ deg){
  int idx = blockIdx.x * 256 + threadIdx.x;   // < NG*NE
  int g = idx >> 15, e = idx & (NE - 1);
  int dst = ei[(g * 2 + 1) * NE + e];
  atomicAdd(&deg[g * NN + dst], 1u);
}

__global__ void k_dinv(const u32* __restrict__ deg, float* __restrict__ dinv){
  int idx = blockIdx.x * 256 + threadIdx.x;   // < NG*NN
  dinv[idx] = rsqrtf((float)(deg[idx] + 1u)); // +1 self loop
}

__global__ void k_scatter(const int* __restrict__ ei, const float* __restrict__ xw,
                          const float* __restrict__ dinv, float* __restrict__ h){
  int idx = blockIdx.x * 256 + threadIdx.x;   // < NG*NE
  int g = idx >> 15, e = idx & (NE - 1);
  int src = ei[g * 2 * NE + e];
  int dst = ei[(g * 2 + 1) * NE + e];
  float c = dinv[g * NN + src] * dinv[g * NN + dst];
  const float4* xr = (const float4*)(xw + (size_t)(g * NN + src) * 32);
  float* hb = h + (size_t)(g * NN + dst) * 32;
  #pragma unroll
  for (int q = 0; q < 8; ++q){
    float4 v = xr[q];
    atomicAdd(hb + q * 4 + 0, v.x * c);
    atomicAdd(hb + q * 4 + 1, v.y * c);
    atomicAdd(hb + q * 4 + 2, v.z * c);
    atomicAdd(hb + q * 4 + 3, v.w * c);
  }
}

// h += dinv^2 * xw + b_gcn   (self-loop message + bias)
__global__ void k_selfbias(const float* __restrict__ xw, const float* __restrict__ dinv,
                           const float* __restrict__ bg, float* __restrict__ h){
  int idx = blockIdx.x * 256 + threadIdx.x;   // < NG*NN*NF
  int g = idx >> 16, rem = idx & (IND - 1);
  int n = rem >> 5, f = rem & 31;
  float d = dinv[g * NN + n];
  h[idx] += d * d * xw[idx] + bg[f];
}

// ---------------- BatchNorm + tanh ----------------

__global__ void k_bnstat(const float* __restrict__ h, float* __restrict__ pstat){
  int g = blockIdx.x >> 3, s = blockIdx.x & 7;
  int t = threadIdx.x, f = t & 31, r = t >> 5;
  float s1 = 0.f, s2 = 0.f;
  for (int it = 0; it < 32; ++it){
    int n = s * 256 + it * 8 + r;
    float v = h[(size_t)(g * NN + n) * 32 + f];
    s1 += v; s2 += v * v;
  }
  __shared__ float l1[256], l2[256];
  l1[t] = s1; l2[t] = s2;
  __syncthreads();
  if (t < 32){
    float a = 0.f, b = 0.f;
    #pragma unroll
    for (int r2 = 0; r2 < 8; ++r2){ a += l1[r2 * 32 + t]; b += l2[r2 * 32 + t]; }
    pstat[((g * 8 + s) * 32 + t) * 2 + 0] = a;
    pstat[((g * 8 + s) * 32 + t) * 2 + 1] = b;
  }
}

__global__ void k_bnfinal(const float* __restrict__ pstat, const float* __restrict__ gamma,
                          const float* __restrict__ beta, float* __restrict__ scale,
                          float* __restrict__ shift){
  int t = threadIdx.x;            // 512 = 16*32
  int g = t >> 5, f = t & 31;
  float s1 = 0.f, s2 = 0.f;
  #pragma unroll
  for (int s = 0; s < 8; ++s){
    s1 += pstat[((g * 8 + s) * 32 + f) * 2 + 0];
    s2 += pstat[((g * 8 + s) * 32 + f) * 2 + 1];
  }
  float mean = s1 * (1.f / NN);
  float var  = s2 * (1.f / NN) - mean * mean;
  float sc = gamma[f] * rsqrtf(var + 1e-5f);
  scale[t] = sc;
  shift[t] = beta[f] - mean * sc;
}

// xs_T[k][g] = tanh(h[g][k]*scale+shift)   k = n*32+f
__global__ void k_norm(const float* __restrict__ h, const float* __restrict__ scale,
                       const float* __restrict__ shift, float* __restrict__ xsT){
  int kk = blockIdx.x * 256 + threadIdx.x;   // < IND
  int f = kk & 31;
  float o[16];
  #pragma unroll
  for (int g = 0; g < 16; ++g){
    float v = h[(size_t)g * IND + kk];
    o[g] = tanhf(v * scale[g * 32 + f] + shift[g * 32 + f]);
  }
  float4* dst = (float4*)(xsT + (size_t)kk * 16);
  dst[0] = make_float4(o[0],  o[1],  o[2],  o[3]);
  dst[1] = make_float4(o[4],  o[5],  o[6],  o[7]);
  dst[2] = make_float4(o[8],  o[9],  o[10], o[11]);
  dst[3] = make_float4(o[12], o[13], o[14], o[15]);
}

// ---------------- Big GEMMs: out[16,N] = A_T[K,16]^T * B[K,N], split-K ----------------

__global__ void k_gemv16(const float* __restrict__ A,   // [K][16]
                         const float* __restrict__ B,   // [K][N]
                         float* __restrict__ part,      // [chunks][16][N]
                         int Nn, int Kc){
  __shared__ float ash[256 * 16];       // Kc <= 256
  int t = threadIdx.x;
  int k0 = blockIdx.y * Kc;
  for (int i = t; i < Kc * 16; i += 256) ash[i] = A[(size_t)k0 * 16 + i];
  __syncthreads();
  int n0 = blockIdx.x * 512 + t * 2;
  float acc[32];
  #pragma unroll
  for (int i = 0; i < 32; ++i) acc[i] = 0.f;
  const float* bp = B + (size_t)k0 * Nn + n0;
  for (int k = 0; k < Kc; ++k){
    float2 bv = *(const float2*)bp;  bp += Nn;
    const float* ap = &ash[k * 16];
    #pragma unroll
    for (int m = 0; m < 16; ++m){
      float a = ap[m];
      acc[2 * m]     += a * bv.x;
      acc[2 * m + 1] += a * bv.y;
    }
  }
  float* pp = part + (size_t)blockIdx.y * 16 * Nn + n0;
  #pragma unroll
  for (int m = 0; m < 16; ++m)
    *(float2*)(pp + (size_t)m * Nn) = make_float2(acc[2 * m], acc[2 * m + 1]);
}

// encoder reduce stage1: 256 chunks -> 8 groups
__global__ void k_encred1(const float* __restrict__ part, float* __restrict__ p2){
  int idx = blockIdx.x * 256 + threadIdx.x;   // < 8*8192
  int out = idx & 8191, grp = idx >> 13;
  const float* p = part + (size_t)grp * 32 * 8192 + out;
  float s = 0.f;
  #pragma unroll 8
  for (int c = 0; c < 32; ++c) s += p[(size_t)c * 8192];
  p2[idx] = s;
}

// encoder reduce stage2 + bias + leaky
__global__ void k_encred2(const float* __restrict__ p2, const float* __restrict__ be,
                          float* __restrict__ henc){
  int out = blockIdx.x * 256 + threadIdx.x;   // < 8192
  int n = out & 511;
  float s = be[n];
  #pragma unroll
  for (int g = 0; g < 8; ++g) s += p2[g * 8192 + out];
  henc[out] = s > 0.f ? s : 0.01f * s;
}

// mean / log_var heads + reparameterize
__global__ void k_heads(const float* __restrict__ henc, const float* __restrict__ Wmu,
                        const float* __restrict__ bmu, const float* __restrict__ Wlv,
                        const float* __restrict__ blv, const float* __restrict__ eps,
                        float* __restrict__ zbuf, float* __restrict__ outp){
  int t = threadIdx.x;
  int l = t & 63, m = blockIdx.x * 4 + (t >> 6);
  const float* hp = henc + m * 512;
  float am = 0.f, av = 0.f;
  for (int k = 0; k < 512; ++k){
    float h = hp[k];
    am += h * Wmu[k * 64 + l];
    av += h * Wlv[k * 64 + l];
  }
  float mean = am + bmu[l];
  float lv   = av + blv[l];
  float z = mean + expf(0.5f * lv) * eps[m * 64 + l];
  zbuf[m * 64 + l] = z;
  outp[1048576 + m * 64 + l] = mean;
  outp[1049600 + m * 64 + l] = lv;
}

// decoder layer 1 -> hd_T[k][m]
__global__ void k_dec1(const float* __restrict__ zbuf, const float* __restrict__ W1,
                       const float* __restrict__ b1, float* __restrict__ hdT){
  int m = blockIdx.x, h = threadIdx.x;   // 16 x 512
  const float* zp = zbuf + m * 64;
  float a = 0.f;
  #pragma unroll
  for (int k = 0; k < 64; ++k) a += zp[k] * W1[k * 512 + h];
  a += b1[h];
  a = a > 0.f ? a : 0.01f * a;
  hdT[h * 16 + m] = a;
}

// decoder reduce (2 k-chunks) + bias -> f32 out
__global__ void k_decred(const float* __restrict__ part, const float* __restrict__ b2,
                         float* __restrict__ outp){
  int idx = blockIdx.x * 256 + threadIdx.x;   // < 16*65536
  int n = idx & 65535;
  outp[idx] = part[idx] + part[1048576 + idx] + b2[n];
}

// ---------------- launch ----------------

extern "C" void kernel_launch(void* const* d_in, const int* in_sizes, int n_in,
                              void* d_out, int out_size, void* d_ws, size_t ws_size,
                              hipStream_t stream){
  const float* x     = (const float*)d_in[0];
  const int*   ei    = (const int*)d_in[1];
  const float* eps   = (const float*)d_in[2];
  const float* Wg    = (const float*)d_in[3];
  const float* bg    = (const float*)d_in[4];
  const float* gamma = (const float*)d_in[5];
  const float* beta  = (const float*)d_in[6];
  const float* Wenc  = (const float*)d_in[7];
  const float* benc  = (const float*)d_in[8];
  const float* Wmu   = (const float*)d_in[9];
  const float* bmu   = (const float*)d_in[10];
  const float* Wlv   = (const float*)d_in[11];
  const float* blv   = (const float*)d_in[12];
  const float* Wd1   = (const float*)d_in[13];
  const float* bd1   = (const float*)d_in[14];
  const float* Wd2   = (const float*)d_in[15];
  const float* bd2   = (const float*)d_in[16];
  float* outp = (float*)d_out;

  char* ws = (char*)d_ws;
  const size_t OFF_XW    = 0;                    // 4 MB, reused as xs_T
  const size_t OFF_H     = 4194304;              // 4 MB
  const size_t OFF_DEG   = 8388608;              // 128 KB
  const size_t OFF_DINV  = 8519680;              // 128 KB
  const size_t OFF_PSTAT = 8650752;              // 32 KB
  const size_t OFF_SCALE = 8683520;              // 2 KB
  const size_t OFF_SHIFT = 8685568;              // 2 KB
  const size_t OFF_HENC  = 8687616;              // 32 KB
  const size_t OFF_Z     = 8720384;              // 4 KB
  const size_t OFF_HDT   = 8724480;              // 32 KB
  const size_t OFF_P2    = 8757248;              // 256 KB
  const size_t OFF_PART  = 9019392;              // 8 MB

  float* xw    = (float*)(ws + OFF_XW);
  float* xsT   = (float*)(ws + OFF_XW);          // alias: xw dead before xs_T written
  float* h     = (float*)(ws + OFF_H);
  u32*   deg   = (u32*)  (ws + OFF_DEG);
  float* dinv  = (float*)(ws + OFF_DINV);
  float* pstat = (float*)(ws + OFF_PSTAT);
  float* scale = (float*)(ws + OFF_SCALE);
  float* shift = (float*)(ws + OFF_SHIFT);
  float* henc  = (float*)(ws + OFF_HENC);
  float* zbuf  = (float*)(ws + OFF_Z);
  float* hdT   = (float*)(ws + OFF_HDT);
  float* p2    = (float*)(ws + OFF_P2);
  float* part  = (float*)(ws + OFF_PART);

  // zero h (4MB) + deg (128KB), contiguous
  hipMemsetAsync(ws + OFF_H, 0, 4194304 + 131072, stream);

  k_xw      <<<4096, 256, 0, stream>>>(x, Wg, xw);
  k_deg     <<<2048, 256, 0, stream>>>(ei, deg);
  k_dinv    <<<128,  256, 0, stream>>>(deg, dinv);
  k_scatter <<<2048, 256, 0, stream>>>(ei, xw, dinv, h);
  k_selfbias<<<4096, 256, 0, stream>>>(xw, dinv, bg, h);
  k_bnstat  <<<128,  256, 0, stream>>>(h, pstat);
  k_bnfinal <<<1,    512, 0, stream>>>(pstat, gamma, beta, scale, shift);
  k_norm    <<<256,  256, 0, stream>>>(h, scale, shift, xsT);

  // encoder: K=65536 in 256 chunks of 256, N=512
  k_gemv16  <<<dim3(1, 256), 256, 0, stream>>>(xsT, Wenc, part, 512, 256);
  k_encred1 <<<256, 256, 0, stream>>>(part, p2);
  k_encred2 <<<32,  256, 0, stream>>>(p2, benc, henc);

  k_heads   <<<4,  256, 0, stream>>>(henc, Wmu, bmu, Wlv, blv, eps, zbuf, outp);
  k_dec1    <<<16, 512, 0, stream>>>(zbuf, Wd1, bd1, hdT);

  // decoder: K=512 in 2 chunks of 256, N=65536
  k_gemv16  <<<dim3(128, 2), 256, 0, stream>>>(hdT, Wd2, part, 65536, 256);
  k_decred  <<<4096, 256, 0, stream>>>(part, bd2, outp);
}

// Round 3
// 246.890 us; speedup vs baseline: 4.5279x; 4.5279x over previous
//
#include <hip/hip_runtime.h>
#include <hip/hip_bf16.h>

// Shapes
#define NG 16
#define NN 2048
#define NF 32
#define NE 32768
#define IND 65536   // NN*NF
#define HD 512
#define LD 64

typedef unsigned int u32;

// ---------------- GCN part ----------------

// xw = x @ W_gcn   (per flat node)
__global__ void k_xw(const float* __restrict__ x, const float* __restrict__ Wg,
                     float* __restrict__ xw){
  __shared__ float ws[32][33];
  __shared__ float xsh[8][32];
  int t = threadIdx.x;
  for (int i = t; i < 1024; i += 256) ws[i >> 5][i & 31] = Wg[i];
  int base = blockIdx.x * 8;            // flat node index (g*NN+n)
  int r = t >> 5, f = t & 31;
  xsh[r][f] = x[(base + r) * 32 + f];
  __syncthreads();
  float acc = 0.f;
  #pragma unroll
  for (int k = 0; k < 32; ++k) acc += xsh[r][k] * ws[k][f];
  xw[(base + r) * 32 + f] = acc;
}

__global__ void k_deg(const int* __restrict__ ei, u32* __restrict__ deg){
  int idx = blockIdx.x * 256 + threadIdx.x;   // < NG*NE
  int g = idx >> 15, e = idx & (NE - 1);
  int dst = ei[(g * 2 + 1) * NE + e];
  atomicAdd(&deg[g * NN + dst], 1u);
}

// per-graph exclusive prefix sum of deg -> CSR offs; also dinv and cursor=0
__global__ void k_prefix(const u32* __restrict__ deg, u32* __restrict__ offs,
                         float* __restrict__ dinv, u32* __restrict__ cursor){
  int g = blockIdx.x, t = threadIdx.x;      // 16 blocks x 256 threads
  const u32* dg = deg + g * NN;
  u32 loc[8]; u32 s = 0;
  #pragma unroll
  for (int i = 0; i < 8; ++i){ loc[i] = s; s += dg[t * 8 + i]; }
  __shared__ u32 bs[256];
  bs[t] = s; __syncthreads();
  for (int d = 1; d < 256; d <<= 1){
    u32 v = (t >= d) ? bs[t - d] : 0u;
    __syncthreads();
    bs[t] += v;
    __syncthreads();
  }
  u32 base = bs[t] - s;                     // exclusive
  #pragma unroll
  for (int i = 0; i < 8; ++i){
    int n = t * 8 + i;
    offs[g * NN + n] = g * NE + base + loc[i];
    dinv[g * NN + n] = rsqrtf((float)(dg[n] + 1u));  // +1 self loop
    cursor[g * NN + n] = 0u;
  }
}

// counting-sort: place src of each edge into its dst bucket
__global__ void k_sortedges(const int* __restrict__ ei, const u32* __restrict__ offs,
                            u32* __restrict__ cursor, u32* __restrict__ sorted){
  int idx = blockIdx.x * 256 + threadIdx.x;   // < NG*NE
  int g = idx >> 15, e = idx & (NE - 1);
  int src = ei[g * 2 * NE + e];
  int dst = ei[(g * 2 + 1) * NE + e];
  u32 pos = atomicAdd(&cursor[g * NN + dst], 1u);
  sorted[offs[g * NN + dst] + pos] = (u32)src;
}

// gather: h[g][n][f] = sum_{src->n} dinv[src]*dinv[n]*xw[src][f] + dinv[n]^2*xw[n][f] + bg[f]
__global__ void k_gather(const u32* __restrict__ sorted, const u32* __restrict__ offs,
                         const u32* __restrict__ deg, const float* __restrict__ dinv,
                         const float* __restrict__ xw, const float* __restrict__ bg,
                         float* __restrict__ h){
  int tid = blockIdx.x * 256 + threadIdx.x;   // < NG*NN*8
  int q = tid & 7, n = (tid >> 3) & (NN - 1), g = tid >> 14;
  int gn = g * NN + n;
  u32 o0 = offs[gn];
  u32 cnt = deg[gn];
  float dn = dinv[gn];
  const float4* xw4 = (const float4*)xw;
  float4 acc = make_float4(0.f, 0.f, 0.f, 0.f);
  for (u32 e = 0; e < cnt; ++e){
    u32 src = sorted[o0 + e];
    float c = dinv[g * NN + src] * dn;
    float4 v = xw4[(size_t)(g * NN + src) * 8 + q];
    acc.x += c * v.x; acc.y += c * v.y; acc.z += c * v.z; acc.w += c * v.w;
  }
  float c2 = dn * dn;
  float4 v = xw4[(size_t)gn * 8 + q];
  float4 b = ((const float4*)bg)[q];
  acc.x += c2 * v.x + b.x; acc.y += c2 * v.y + b.y;
  acc.z += c2 * v.z + b.z; acc.w += c2 * v.w + b.w;
  ((float4*)h)[(size_t)gn * 8 + q] = acc;
}

// ---------------- BatchNorm + tanh ----------------

__global__ void k_bnstat(const float* __restrict__ h, float* __restrict__ pstat){
  int g = blockIdx.x >> 3, s = blockIdx.x & 7;
  int t = threadIdx.x, f = t & 31, r = t >> 5;
  float s1 = 0.f, s2 = 0.f;
  for (int it = 0; it < 32; ++it){
    int n = s * 256 + it * 8 + r;
    float v = h[(size_t)(g * NN + n) * 32 + f];
    s1 += v; s2 += v * v;
  }
  __shared__ float l1[256], l2[256];
  l1[t] = s1; l2[t] = s2;
  __syncthreads();
  if (t < 32){
    float a = 0.f, b = 0.f;
    #pragma unroll
    for (int r2 = 0; r2 < 8; ++r2){ a += l1[r2 * 32 + t]; b += l2[r2 * 32 + t]; }
    pstat[((g * 8 + s) * 32 + t) * 2 + 0] = a;
    pstat[((g * 8 + s) * 32 + t) * 2 + 1] = b;
  }
}

__global__ void k_bnfinal(const float* __restrict__ pstat, const float* __restrict__ gamma,
                          const float* __restrict__ beta, float* __restrict__ scale,
                          float* __restrict__ shift){
  int t = threadIdx.x;            // 512 = 16*32
  int g = t >> 5, f = t & 31;
  float s1 = 0.f, s2 = 0.f;
  #pragma unroll
  for (int s = 0; s < 8; ++s){
    s1 += pstat[((g * 8 + s) * 32 + f) * 2 + 0];
    s2 += pstat[((g * 8 + s) * 32 + f) * 2 + 1];
  }
  float mean = s1 * (1.f / NN);
  float var  = s2 * (1.f / NN) - mean * mean;
  float sc = gamma[f] * rsqrtf(var + 1e-5f);
  scale[t] = sc;
  shift[t] = beta[f] - mean * sc;
}

// xs_T[k][g] = tanh(h[g][k]*scale+shift)   k = n*32+f
__global__ void k_norm(const float* __restrict__ h, const float* __restrict__ scale,
                       const float* __restrict__ shift, float* __restrict__ xsT){
  int kk = blockIdx.x * 256 + threadIdx.x;   // < IND
  int f = kk & 31;
  float o[16];
  #pragma unroll
  for (int g = 0; g < 16; ++g){
    float v = h[(size_t)g * IND + kk];
    o[g] = tanhf(v * scale[g * 32 + f] + shift[g * 32 + f]);
  }
  float4* dst = (float4*)(xsT + (size_t)kk * 16);
  dst[0] = make_float4(o[0],  o[1],  o[2],  o[3]);
  dst[1] = make_float4(o[4],  o[5],  o[6],  o[7]);
  dst[2] = make_float4(o[8],  o[9],  o[10], o[11]);
  dst[3] = make_float4(o[12], o[13], o[14], o[15]);
}

// ---------------- Encoder GEMM: part[chunk][16][512], split-K 256x256 ----------------

__global__ void k_gemvenc(const float* __restrict__ A,   // [K][16] = xsT
                          const float* __restrict__ B,   // [K][512] = Wenc
                          float* __restrict__ part){
  __shared__ float ash[256 * 16];
  int t = threadIdx.x;                 // 512 threads
  int k0 = blockIdx.x * 256;           // 256 chunks
  for (int i = t; i < 4096; i += 512) ash[i] = A[(size_t)k0 * 16 + i];
  __syncthreads();
  float acc[16];
  #pragma unroll
  for (int m = 0; m < 16; ++m) acc[m] = 0.f;
  const float* bp = B + (size_t)k0 * 512 + t;
  for (int k = 0; k < 256; ++k){
    float bv = *bp; bp += 512;
    const float* ap = &ash[k * 16];
    #pragma unroll
    for (int m = 0; m < 16; ++m) acc[m] += ap[m] * bv;
  }
  float* pp = part + (size_t)blockIdx.x * 16 * 512 + t;
  #pragma unroll
  for (int m = 0; m < 16; ++m) pp[(size_t)m * 512] = acc[m];
}

// encoder reduce stage1: 256 chunks -> 8 groups
__global__ void k_encred1(const float* __restrict__ part, float* __restrict__ p2){
  int idx = blockIdx.x * 256 + threadIdx.x;   // < 8*8192
  int out = idx & 8191, grp = idx >> 13;
  const float* p = part + (size_t)grp * 32 * 8192 + out;
  float s = 0.f;
  #pragma unroll 8
  for (int c = 0; c < 32; ++c) s += p[(size_t)c * 8192];
  p2[idx] = s;
}

// encoder reduce stage2 + bias + leaky
__global__ void k_encred2(const float* __restrict__ p2, const float* __restrict__ be,
                          float* __restrict__ henc){
  int out = blockIdx.x * 256 + threadIdx.x;   // < 8192
  int n = out & 511;
  float s = be[n];
  #pragma unroll
  for (int g = 0; g < 8; ++g) s += p2[g * 8192 + out];
  henc[out] = s > 0.f ? s : 0.01f * s;
}

// mean / log_var heads + reparameterize
__global__ void k_heads(const float* __restrict__ henc, const float* __restrict__ Wmu,
                        const float* __restrict__ bmu, const float* __restrict__ Wlv,
                        const float* __restrict__ blv, const float* __restrict__ eps,
                        float* __restrict__ zbuf, float* __restrict__ outp){
  int t = threadIdx.x;
  int l = t & 63, m = blockIdx.x * 4 + (t >> 6);
  const float* hp = henc + m * 512;
  float am = 0.f, av = 0.f;
  for (int k = 0; k < 512; ++k){
    float h = hp[k];
    am += h * Wmu[k * 64 + l];
    av += h * Wlv[k * 64 + l];
  }
  float mean = am + bmu[l];
  float lv   = av + blv[l];
  float z = mean + expf(0.5f * lv) * eps[m * 64 + l];
  zbuf[m * 64 + l] = z;
  outp[1048576 + m * 64 + l] = mean;
  outp[1049600 + m * 64 + l] = lv;
}

// decoder layer 1 -> hd_T[k][m]
__global__ void k_dec1(const float* __restrict__ zbuf, const float* __restrict__ W1,
                       const float* __restrict__ b1, float* __restrict__ hdT){
  int m = blockIdx.x, h = threadIdx.x;   // 16 x 512
  const float* zp = zbuf + m * 64;
  float a = 0.f;
  #pragma unroll
  for (int k = 0; k < 64; ++k) a += zp[k] * W1[k * 512 + h];
  a += b1[h];
  a = a > 0.f ? a : 0.01f * a;
  hdT[h * 16 + m] = a;
}

// ---------------- Decoder GEMM: full K=512, direct output + bias ----------------

__global__ void k_gemvdec(const float* __restrict__ A,    // [512][16] = hdT
                          const float* __restrict__ B,    // [512][65536] = Wd2
                          const float* __restrict__ bias, // [65536]
                          float* __restrict__ outp){
  __shared__ float ash[512 * 16];      // 32 KB
  int t = threadIdx.x;                 // 256 threads
  for (int i = t; i < 8192; i += 256) ash[i] = A[i];
  __syncthreads();
  int n = blockIdx.x * 256 + t;        // 256 blocks cover 65536
  float acc[16];
  #pragma unroll
  for (int m = 0; m < 16; ++m) acc[m] = 0.f;
  const float* bp = B + n;
  for (int k = 0; k < 512; ++k){
    float bv = *bp; bp += 65536;
    const float* ap = &ash[k * 16];
    #pragma unroll
    for (int m = 0; m < 16; ++m) acc[m] += ap[m] * bv;
  }
  float bb = bias[n];
  #pragma unroll
  for (int m = 0; m < 16; ++m) outp[(size_t)m * 65536 + n] = acc[m] + bb;
}

// ---------------- launch ----------------

extern "C" void kernel_launch(void* const* d_in, const int* in_sizes, int n_in,
                              void* d_out, int out_size, void* d_ws, size_t ws_size,
                              hipStream_t stream){
  const float* x     = (const float*)d_in[0];
  const int*   ei    = (const int*)d_in[1];
  const float* eps   = (const float*)d_in[2];
  const float* Wg    = (const float*)d_in[3];
  const float* bg    = (const float*)d_in[4];
  const float* gamma = (const float*)d_in[5];
  const float* beta  = (const float*)d_in[6];
  const float* Wenc  = (const float*)d_in[7];
  const float* benc  = (const float*)d_in[8];
  const float* Wmu   = (const float*)d_in[9];
  const float* bmu   = (const float*)d_in[10];
  const float* Wlv   = (const float*)d_in[11];
  const float* blv   = (const float*)d_in[12];
  const float* Wd1   = (const float*)d_in[13];
  const float* bd1   = (const float*)d_in[14];
  const float* Wd2   = (const float*)d_in[15];
  const float* bd2   = (const float*)d_in[16];
  float* outp = (float*)d_out;

  char* ws = (char*)d_ws;
  const size_t OFF_XW    = 0;                    // 4 MB, reused as xs_T
  const size_t OFF_H     = 4194304;              // 4 MB
  const size_t OFF_DEG   = 8388608;              // 128 KB
  const size_t OFF_DINV  = 8519680;              // 128 KB
  const size_t OFF_PSTAT = 8650752;              // 32 KB
  const size_t OFF_SCALE = 8683520;              // 2 KB
  const size_t OFF_SHIFT = 8685568;              // 2 KB
  const size_t OFF_HENC  = 8687616;              // 32 KB
  const size_t OFF_Z     = 8720384;              // 4 KB
  const size_t OFF_HDT   = 8724480;              // 32 KB
  const size_t OFF_P2    = 8757248;              // 256 KB
  const size_t OFF_PART  = 9019392;              // 8 MB (enc partials)
  // aliases inside PART region: all dead before k_gemvenc writes part
  const size_t OFF_SORT  = OFF_PART;             // 2 MB  (sorted src, NG*NE u32)
  const size_t OFF_OFFS  = OFF_PART + 2097152;   // 128 KB (CSR offsets)
  const size_t OFF_CUR   = OFF_PART + 2228224;   // 128 KB (bucket cursors)

  float* xw     = (float*)(ws + OFF_XW);
  float* xsT    = (float*)(ws + OFF_XW);         // alias: xw dead before xs_T written
  float* h      = (float*)(ws + OFF_H);
  u32*   deg    = (u32*)  (ws + OFF_DEG);
  float* dinv   = (float*)(ws + OFF_DINV);
  float* pstat  = (float*)(ws + OFF_PSTAT);
  float* scale  = (float*)(ws + OFF_SCALE);
  float* shift  = (float*)(ws + OFF_SHIFT);
  float* henc   = (float*)(ws + OFF_HENC);
  float* zbuf   = (float*)(ws + OFF_Z);
  float* hdT    = (float*)(ws + OFF_HDT);
  float* p2     = (float*)(ws + OFF_P2);
  float* part   = (float*)(ws + OFF_PART);
  u32*   sorted = (u32*)  (ws + OFF_SORT);
  u32*   offs   = (u32*)  (ws + OFF_OFFS);
  u32*   cursor = (u32*)  (ws + OFF_CUR);

  hipMemsetAsync(ws + OFF_DEG, 0, 131072, stream);   // deg only

  k_xw       <<<4096, 256, 0, stream>>>(x, Wg, xw);
  k_deg      <<<2048, 256, 0, stream>>>(ei, deg);
  k_prefix   <<<16,   256, 0, stream>>>(deg, offs, dinv, cursor);
  k_sortedges<<<2048, 256, 0, stream>>>(ei, offs, cursor, sorted);
  k_gather   <<<1024, 256, 0, stream>>>(sorted, offs, deg, dinv, xw, bg, h);
  k_bnstat   <<<128,  256, 0, stream>>>(h, pstat);
  k_bnfinal  <<<1,    512, 0, stream>>>(pstat, gamma, beta, scale, shift);
  k_norm     <<<256,  256, 0, stream>>>(h, scale, shift, xsT);

  // encoder: K=65536 in 256 chunks of 256, N=512
  k_gemvenc  <<<256, 512, 0, stream>>>(xsT, Wenc, part);
  k_encred1  <<<256, 256, 0, stream>>>(part, p2);
  k_encred2  <<<32,  256, 0, stream>>>(p2, benc, henc);

  k_heads    <<<4,  256, 0, stream>>>(henc, Wmu, bmu, Wlv, blv, eps, zbuf, outp);
  k_dec1     <<<16, 512, 0, stream>>>(zbuf, Wd1, bd1, hdT);

  // decoder: full K=512, direct write with bias
  k_gemvdec  <<<256, 256, 0, stream>>>(hdT, Wd2, bd2, outp);
}

// Round 4
// 205.301 us; speedup vs baseline: 5.4451x; 1.2026x over previous
//
#include <hip/hip_runtime.h>
#include <hip/hip_bf16.h>

// Shapes
#define NG 16
#define NN 2048
#define NF 32
#define NE 32768
#define IND 65536   // NN*NF
#define HD 512
#define LD 64

typedef unsigned int u32;

// ---------------- GCN part ----------------

// xw = x @ W_gcn   (per flat node)
__global__ void k_xw(const float* __restrict__ x, const float* __restrict__ Wg,
                     float* __restrict__ xw){
  __shared__ float ws[32][33];
  __shared__ float xsh[8][32];
  int t = threadIdx.x;
  for (int i = t; i < 1024; i += 256) ws[i >> 5][i & 31] = Wg[i];
  int base = blockIdx.x * 8;            // flat node index (g*NN+n)
  int r = t >> 5, f = t & 31;
  xsh[r][f] = x[(base + r) * 32 + f];
  __syncthreads();
  float acc = 0.f;
  #pragma unroll
  for (int k = 0; k < 32; ++k) acc += xsh[r][k] * ws[k][f];
  xw[(base + r) * 32 + f] = acc;
}

__global__ void k_deg(const int* __restrict__ ei, u32* __restrict__ deg){
  int idx = blockIdx.x * 256 + threadIdx.x;   // < NG*NE
  int g = idx >> 15, e = idx & (NE - 1);
  int dst = ei[(g * 2 + 1) * NE + e];
  atomicAdd(&deg[g * NN + dst], 1u);
}

// per-graph exclusive prefix sum of deg -> CSR offs; also dinv and cursor=0
__global__ void k_prefix(const u32* __restrict__ deg, u32* __restrict__ offs,
                         float* __restrict__ dinv, u32* __restrict__ cursor){
  int g = blockIdx.x, t = threadIdx.x;      // 16 blocks x 256 threads
  const u32* dg = deg + g * NN;
  u32 loc[8]; u32 s = 0;
  #pragma unroll
  for (int i = 0; i < 8; ++i){ loc[i] = s; s += dg[t * 8 + i]; }
  __shared__ u32 bs[256];
  bs[t] = s; __syncthreads();
  for (int d = 1; d < 256; d <<= 1){
    u32 v = (t >= d) ? bs[t - d] : 0u;
    __syncthreads();
    bs[t] += v;
    __syncthreads();
  }
  u32 base = bs[t] - s;                     // exclusive
  #pragma unroll
  for (int i = 0; i < 8; ++i){
    int n = t * 8 + i;
    offs[g * NN + n] = g * NE + base + loc[i];
    dinv[g * NN + n] = rsqrtf((float)(dg[n] + 1u));  // +1 self loop
    cursor[g * NN + n] = 0u;
  }
}

// counting-sort: place src of each edge into its dst bucket
__global__ void k_sortedges(const int* __restrict__ ei, const u32* __restrict__ offs,
                            u32* __restrict__ cursor, u32* __restrict__ sorted){
  int idx = blockIdx.x * 256 + threadIdx.x;   // < NG*NE
  int g = idx >> 15, e = idx & (NE - 1);
  int src = ei[g * 2 * NE + e];
  int dst = ei[(g * 2 + 1) * NE + e];
  u32 pos = atomicAdd(&cursor[g * NN + dst], 1u);
  sorted[offs[g * NN + dst] + pos] = (u32)src;
}

// gather: h[g][n][f] = sum_{src->n} dinv[src]*dinv[n]*xw[src][f] + dinv[n]^2*xw[n][f] + bg[f]
__global__ void k_gather(const u32* __restrict__ sorted, const u32* __restrict__ offs,
                         const u32* __restrict__ deg, const float* __restrict__ dinv,
                         const float* __restrict__ xw, const float* __restrict__ bg,
                         float* __restrict__ h){
  int tid = blockIdx.x * 256 + threadIdx.x;   // < NG*NN*8
  int q = tid & 7, n = (tid >> 3) & (NN - 1), g = tid >> 14;
  int gn = g * NN + n;
  u32 o0 = offs[gn];
  u32 cnt = deg[gn];
  float dn = dinv[gn];
  const float4* xw4 = (const float4*)xw;
  float4 acc = make_float4(0.f, 0.f, 0.f, 0.f);
  for (u32 e = 0; e < cnt; ++e){
    u32 src = sorted[o0 + e];
    float c = dinv[g * NN + src] * dn;
    float4 v = xw4[(size_t)(g * NN + src) * 8 + q];
    acc.x += c * v.x; acc.y += c * v.y; acc.z += c * v.z; acc.w += c * v.w;
  }
  float c2 = dn * dn;
  float4 v = xw4[(size_t)gn * 8 + q];
  float4 b = ((const float4*)bg)[q];
  acc.x += c2 * v.x + b.x; acc.y += c2 * v.y + b.y;
  acc.z += c2 * v.z + b.z; acc.w += c2 * v.w + b.w;
  ((float4*)h)[(size_t)gn * 8 + q] = acc;
}

// ---------------- BatchNorm + tanh ----------------

__global__ void k_bnstat(const float* __restrict__ h, float* __restrict__ pstat){
  int g = blockIdx.x >> 3, s = blockIdx.x & 7;
  int t = threadIdx.x, f = t & 31, r = t >> 5;
  float s1 = 0.f, s2 = 0.f;
  for (int it = 0; it < 32; ++it){
    int n = s * 256 + it * 8 + r;
    float v = h[(size_t)(g * NN + n) * 32 + f];
    s1 += v; s2 += v * v;
  }
  __shared__ float l1[256], l2[256];
  l1[t] = s1; l2[t] = s2;
  __syncthreads();
  if (t < 32){
    float a = 0.f, b = 0.f;
    #pragma unroll
    for (int r2 = 0; r2 < 8; ++r2){ a += l1[r2 * 32 + t]; b += l2[r2 * 32 + t]; }
    pstat[((g * 8 + s) * 32 + t) * 2 + 0] = a;
    pstat[((g * 8 + s) * 32 + t) * 2 + 1] = b;
  }
}

__global__ void k_bnfinal(const float* __restrict__ pstat, const float* __restrict__ gamma,
                          const float* __restrict__ beta, float* __restrict__ scale,
                          float* __restrict__ shift){
  int t = threadIdx.x;            // 512 = 16*32
  int g = t >> 5, f = t & 31;
  float s1 = 0.f, s2 = 0.f;
  #pragma unroll
  for (int s = 0; s < 8; ++s){
    s1 += pstat[((g * 8 + s) * 32 + f) * 2 + 0];
    s2 += pstat[((g * 8 + s) * 32 + f) * 2 + 1];
  }
  float mean = s1 * (1.f / NN);
  float var  = s2 * (1.f / NN) - mean * mean;
  float sc = gamma[f] * rsqrtf(var + 1e-5f);
  scale[t] = sc;
  shift[t] = beta[f] - mean * sc;
}

// xs_T[k][g] = tanh(h[g][k]*scale+shift)   k = n*32+f
__global__ void k_norm(const float* __restrict__ h, const float* __restrict__ scale,
                       const float* __restrict__ shift, float* __restrict__ xsT){
  int kk = blockIdx.x * 256 + threadIdx.x;   // < IND
  int f = kk & 31;
  float o[16];
  #pragma unroll
  for (int g = 0; g < 16; ++g){
    float v = h[(size_t)g * IND + kk];
    o[g] = tanhf(v * scale[g * 32 + f] + shift[g * 32 + f]);
  }
  float4* dst = (float4*)(xsT + (size_t)kk * 16);
  dst[0] = make_float4(o[0],  o[1],  o[2],  o[3]);
  dst[1] = make_float4(o[4],  o[5],  o[6],  o[7]);
  dst[2] = make_float4(o[8],  o[9],  o[10], o[11]);
  dst[3] = make_float4(o[12], o[13], o[14], o[15]);
}

// ---------------- Encoder GEMM: part[chunk][16][512], split-K 256x256 ----------------

__global__ __launch_bounds__(512) void k_gemvenc(const float* __restrict__ A,   // [K][16] = xsT
                          const float* __restrict__ B,   // [K][512] = Wenc
                          float* __restrict__ part){
  __shared__ float ash[256 * 16];
  int t = threadIdx.x;                 // 512 threads
  int k0 = blockIdx.x * 256;           // 256 chunks
  for (int i = t; i < 4096; i += 512) ash[i] = A[(size_t)k0 * 16 + i];
  __syncthreads();
  float acc[16];
  #pragma unroll
  for (int m = 0; m < 16; ++m) acc[m] = 0.f;
  const float* bp = B + (size_t)k0 * 512 + t;
  for (int kk = 0; kk < 256; kk += 8){
    float bv[8];
    #pragma unroll
    for (int u = 0; u < 8; ++u) bv[u] = bp[(size_t)(kk + u) * 512];
    #pragma unroll
    for (int u = 0; u < 8; ++u){
      const float* ap = &ash[(kk + u) * 16];
      #pragma unroll
      for (int m = 0; m < 16; ++m) acc[m] += ap[m] * bv[u];
    }
  }
  float* pp = part + (size_t)blockIdx.x * 16 * 512 + t;
  #pragma unroll
  for (int m = 0; m < 16; ++m) pp[(size_t)m * 512] = acc[m];
}

// encoder reduce stage1: 256 chunks -> 8 groups
__global__ void k_encred1(const float* __restrict__ part, float* __restrict__ p2){
  int idx = blockIdx.x * 256 + threadIdx.x;   // < 8*8192
  int out = idx & 8191, grp = idx >> 13;
  const float* p = part + (size_t)grp * 32 * 8192 + out;
  float s = 0.f;
  #pragma unroll 8
  for (int c = 0; c < 32; ++c) s += p[(size_t)c * 8192];
  p2[idx] = s;
}

// encoder reduce stage2 + bias + leaky
__global__ void k_encred2(const float* __restrict__ p2, const float* __restrict__ be,
                          float* __restrict__ henc){
  int out = blockIdx.x * 256 + threadIdx.x;   // < 8192
  int n = out & 511;
  float s = be[n];
  #pragma unroll
  for (int g = 0; g < 8; ++g) s += p2[g * 8192 + out];
  henc[out] = s > 0.f ? s : 0.01f * s;
}

// mean / log_var heads + reparameterize
__global__ void k_heads(const float* __restrict__ henc, const float* __restrict__ Wmu,
                        const float* __restrict__ bmu, const float* __restrict__ Wlv,
                        const float* __restrict__ blv, const float* __restrict__ eps,
                        float* __restrict__ zbuf, float* __restrict__ outp){
  int t = threadIdx.x;
  int l = t & 63, m = blockIdx.x * 4 + (t >> 6);
  const float* hp = henc + m * 512;
  float am = 0.f, av = 0.f;
  for (int k = 0; k < 512; ++k){
    float h = hp[k];
    am += h * Wmu[k * 64 + l];
    av += h * Wlv[k * 64 + l];
  }
  float mean = am + bmu[l];
  float lv   = av + blv[l];
  float z = mean + expf(0.5f * lv) * eps[m * 64 + l];
  zbuf[m * 64 + l] = z;
  outp[1048576 + m * 64 + l] = mean;
  outp[1049600 + m * 64 + l] = lv;
}

// decoder layer 1 -> hd_T[k][m]
__global__ void k_dec1(const float* __restrict__ zbuf, const float* __restrict__ W1,
                       const float* __restrict__ b1, float* __restrict__ hdT){
  int m = blockIdx.x, h = threadIdx.x;   // 16 x 512
  const float* zp = zbuf + m * 64;
  float a = 0.f;
  #pragma unroll
  for (int k = 0; k < 64; ++k) a += zp[k] * W1[k * 512 + h];
  a += b1[h];
  a = a > 0.f ? a : 0.01f * a;
  hdT[h * 16 + m] = a;
}

// ---------------- Decoder GEMM: K=512 split 2x256, partials ----------------

__global__ __launch_bounds__(256) void k_gemvdec(const float* __restrict__ A,    // [512][16] = hdT
                          const float* __restrict__ B,    // [512][65536] = Wd2
                          float* __restrict__ part){      // [2][16][65536]
  __shared__ float ash[256 * 16];      // 16 KB
  int t = threadIdx.x;                 // 256 threads
  int ks = blockIdx.x & 1;
  int nb = blockIdx.x >> 1;            // 256 n-tiles
  for (int i = t; i < 4096; i += 256) ash[i] = A[ks * 4096 + i];
  __syncthreads();
  int n = nb * 256 + t;
  float acc[16];
  #pragma unroll
  for (int m = 0; m < 16; ++m) acc[m] = 0.f;
  const float* bp = B + (size_t)ks * 256 * 65536 + n;
  for (int kk = 0; kk < 256; kk += 8){
    float bv[8];
    #pragma unroll
    for (int u = 0; u < 8; ++u) bv[u] = bp[(size_t)(kk + u) * 65536];
    #pragma unroll
    for (int u = 0; u < 8; ++u){
      const float* ap = &ash[(kk + u) * 16];
      #pragma unroll
      for (int m = 0; m < 16; ++m) acc[m] += ap[m] * bv[u];
    }
  }
  float* pp = part + (size_t)ks * 16 * 65536 + n;
  #pragma unroll
  for (int m = 0; m < 16; ++m) pp[(size_t)m * 65536] = acc[m];
}

// decoder reduce (2 k-chunks) + bias -> f32 out
__global__ void k_decred(const float* __restrict__ part, const float* __restrict__ b2,
                         float* __restrict__ outp){
  int idx = blockIdx.x * 256 + threadIdx.x;   // < 16*65536
  int n = idx & 65535;
  outp[idx] = part[idx] + part[1048576 + idx] + b2[n];
}

// ---------------- launch ----------------

extern "C" void kernel_launch(void* const* d_in, const int* in_sizes, int n_in,
                              void* d_out, int out_size, void* d_ws, size_t ws_size,
                              hipStream_t stream){
  const float* x     = (const float*)d_in[0];
  const int*   ei    = (const int*)d_in[1];
  const float* eps   = (const float*)d_in[2];
  const float* Wg    = (const float*)d_in[3];
  const float* bg    = (const float*)d_in[4];
  const float* gamma = (const float*)d_in[5];
  const float* beta  = (const float*)d_in[6];
  const float* Wenc  = (const float*)d_in[7];
  const float* benc  = (const float*)d_in[8];
  const float* Wmu   = (const float*)d_in[9];
  const float* bmu   = (const float*)d_in[10];
  const float* Wlv   = (const float*)d_in[11];
  const float* blv   = (const float*)d_in[12];
  const float* Wd1   = (const float*)d_in[13];
  const float* bd1   = (const float*)d_in[14];
  const float* Wd2   = (const float*)d_in[15];
  const float* bd2   = (const float*)d_in[16];
  float* outp = (float*)d_out;

  char* ws = (char*)d_ws;
  const size_t OFF_XW    = 0;                    // 4 MB, reused as xs_T
  const size_t OFF_H     = 4194304;              // 4 MB
  const size_t OFF_DEG   = 8388608;              // 128 KB
  const size_t OFF_DINV  = 8519680;              // 128 KB
  const size_t OFF_PSTAT = 8650752;              // 32 KB
  const size_t OFF_SCALE = 8683520;              // 2 KB
  const size_t OFF_SHIFT = 8685568;              // 2 KB
  const size_t OFF_HENC  = 8687616;              // 32 KB
  const size_t OFF_Z     = 8720384;              // 4 KB
  const size_t OFF_HDT   = 8724480;              // 32 KB
  const size_t OFF_P2    = 8757248;              // 256 KB
  const size_t OFF_PART  = 9019392;              // 8 MB (enc partials / dec partials)
  // aliases inside PART region: all dead before k_gemvenc writes part
  const size_t OFF_SORT  = OFF_PART;             // 2 MB  (sorted src, NG*NE u32)
  const size_t OFF_OFFS  = OFF_PART + 2097152;   // 128 KB (CSR offsets)
  const size_t OFF_CUR   = OFF_PART + 2228224;   // 128 KB (bucket cursors)

  float* xw     = (float*)(ws + OFF_XW);
  float* xsT    = (float*)(ws + OFF_XW);         // alias: xw dead before xs_T written
  float* h      = (float*)(ws + OFF_H);
  u32*   deg    = (u32*)  (ws + OFF_DEG);
  float* dinv   = (float*)(ws + OFF_DINV);
  float* pstat  = (float*)(ws + OFF_PSTAT);
  float* scale  = (float*)(ws + OFF_SCALE);
  float* shift  = (float*)(ws + OFF_SHIFT);
  float* henc   = (float*)(ws + OFF_HENC);
  float* zbuf   = (float*)(ws + OFF_Z);
  float* hdT    = (float*)(ws + OFF_HDT);
  float* p2     = (float*)(ws + OFF_P2);
  float* part   = (float*)(ws + OFF_PART);
  u32*   sorted = (u32*)  (ws + OFF_SORT);
  u32*   offs   = (u32*)  (ws + OFF_OFFS);
  u32*   cursor = (u32*)  (ws + OFF_CUR);

  hipMemsetAsync(ws + OFF_DEG, 0, 131072, stream);   // deg only

  k_xw       <<<4096, 256, 0, stream>>>(x, Wg, xw);
  k_deg      <<<2048, 256, 0, stream>>>(ei, deg);
  k_prefix   <<<16,   256, 0, stream>>>(deg, offs, dinv, cursor);
  k_sortedges<<<2048, 256, 0, stream>>>(ei, offs, cursor, sorted);
  k_gather   <<<1024, 256, 0, stream>>>(sorted, offs, deg, dinv, xw, bg, h);
  k_bnstat   <<<128,  256, 0, stream>>>(h, pstat);
  k_bnfinal  <<<1,    512, 0, stream>>>(pstat, gamma, beta, scale, shift);
  k_norm     <<<256,  256, 0, stream>>>(h, scale, shift, xsT);

  // encoder: K=65536 in 256 chunks of 256, N=512
  k_gemvenc  <<<256, 512, 0, stream>>>(xsT, Wenc, part);
  k_encred1  <<<256, 256, 0, stream>>>(part, p2);
  k_encred2  <<<32,  256, 0, stream>>>(p2, benc, henc);

  k_heads    <<<4,  256, 0, stream>>>(henc, Wmu, bmu, Wlv, blv, eps, zbuf, outp);
  k_dec1     <<<16, 512, 0, stream>>>(zbuf, Wd1, bd1, hdT);

  // decoder: K=512 split into 2x256, 512 blocks, then reduce+bias
  k_gemvdec  <<<512, 256, 0, stream>>>(hdT, Wd2, part);
  k_decred   <<<4096, 256, 0, stream>>>(part, bd2, outp);
}

// Round 5
// 195.238 us; speedup vs baseline: 5.7258x; 1.0515x over previous
//
#include <hip/hip_runtime.h>
#include <hip/hip_bf16.h>

// Shapes
#define NG 16
#define NN 2048
#define NF 32
#define NE 32768
#define IND 65536   // NN*NF
#define HD 512
#define LD 64

typedef unsigned int u32;

// ---------------- GCN part ----------------

// xw = x @ W_gcn   (per flat node)
__global__ void k_xw(const float* __restrict__ x, const float* __restrict__ Wg,
                     float* __restrict__ xw){
  __shared__ float ws[32][33];
  __shared__ float xsh[8][32];
  int t = threadIdx.x;
  for (int i = t; i < 1024; i += 256) ws[i >> 5][i & 31] = Wg[i];
  int base = blockIdx.x * 8;            // flat node index (g*NN+n)
  int r = t >> 5, f = t & 31;
  xsh[r][f] = x[(base + r) * 32 + f];
  __syncthreads();
  float acc = 0.f;
  #pragma unroll
  for (int k = 0; k < 32; ++k) acc += xsh[r][k] * ws[k][f];
  xw[(base + r) * 32 + f] = acc;
}

__global__ void k_deg(const int* __restrict__ ei, u32* __restrict__ deg){
  int idx = blockIdx.x * 256 + threadIdx.x;   // < NG*NE
  int g = idx >> 15, e = idx & (NE - 1);
  int dst = ei[(g * 2 + 1) * NE + e];
  atomicAdd(&deg[g * NN + dst], 1u);
}

// per-graph exclusive prefix sum of deg -> CSR offs; also dinv and cursor=0
__global__ void k_prefix(const u32* __restrict__ deg, u32* __restrict__ offs,
                         float* __restrict__ dinv, u32* __restrict__ cursor){
  int g = blockIdx.x, t = threadIdx.x;      // 16 blocks x 256 threads
  const u32* dg = deg + g * NN;
  u32 loc[8]; u32 s = 0;
  #pragma unroll
  for (int i = 0; i < 8; ++i){ loc[i] = s; s += dg[t * 8 + i]; }
  __shared__ u32 bs[256];
  bs[t] = s; __syncthreads();
  for (int d = 1; d < 256; d <<= 1){
    u32 v = (t >= d) ? bs[t - d] : 0u;
    __syncthreads();
    bs[t] += v;
    __syncthreads();
  }
  u32 base = bs[t] - s;                     // exclusive
  #pragma unroll
  for (int i = 0; i < 8; ++i){
    int n = t * 8 + i;
    offs[g * NN + n] = g * NE + base + loc[i];
    dinv[g * NN + n] = rsqrtf((float)(dg[n] + 1u));  // +1 self loop
    cursor[g * NN + n] = 0u;
  }
}

// counting-sort: place src of each edge into its dst bucket
__global__ void k_sortedges(const int* __restrict__ ei, const u32* __restrict__ offs,
                            u32* __restrict__ cursor, u32* __restrict__ sorted){
  int idx = blockIdx.x * 256 + threadIdx.x;   // < NG*NE
  int g = idx >> 15, e = idx & (NE - 1);
  int src = ei[g * 2 * NE + e];
  int dst = ei[(g * 2 + 1) * NE + e];
  u32 pos = atomicAdd(&cursor[g * NN + dst], 1u);
  sorted[offs[g * NN + dst] + pos] = (u32)src;
}

// gather: h[g][n][f] = sum_{src->n} dinv[src]*dinv[n]*xw[src][f] + dinv[n]^2*xw[n][f] + bg[f]
// each thread handles 2 float4 quads (32B) of one node
__global__ void k_gather(const u32* __restrict__ sorted, const u32* __restrict__ offs,
                         const u32* __restrict__ deg, const float* __restrict__ dinv,
                         const float* __restrict__ xw, const float* __restrict__ bg,
                         float* __restrict__ h){
  int tid = blockIdx.x * 256 + threadIdx.x;   // < NG*NN*4
  int qp = tid & 3, n = (tid >> 2) & (NN - 1), g = tid >> 13;
  int gn = g * NN + n;
  u32 o0 = offs[gn];
  u32 cnt = deg[gn];
  float dn = dinv[gn];
  const float4* xw4 = (const float4*)xw;
  float4 a0 = make_float4(0.f,0.f,0.f,0.f), a1 = a0;
  for (u32 e = 0; e < cnt; ++e){
    u32 src = sorted[o0 + e];
    float c = dinv[g * NN + src] * dn;
    const float4* xr = xw4 + (size_t)(g * NN + src) * 8 + qp * 2;
    float4 v0 = xr[0], v1 = xr[1];
    a0.x += c*v0.x; a0.y += c*v0.y; a0.z += c*v0.z; a0.w += c*v0.w;
    a1.x += c*v1.x; a1.y += c*v1.y; a1.z += c*v1.z; a1.w += c*v1.w;
  }
  float c2 = dn * dn;
  const float4* xr = xw4 + (size_t)gn * 8 + qp * 2;
  float4 v0 = xr[0], v1 = xr[1];
  float4 b0 = ((const float4*)bg)[qp * 2], b1 = ((const float4*)bg)[qp * 2 + 1];
  a0.x += c2*v0.x + b0.x; a0.y += c2*v0.y + b0.y; a0.z += c2*v0.z + b0.z; a0.w += c2*v0.w + b0.w;
  a1.x += c2*v1.x + b1.x; a1.y += c2*v1.y + b1.y; a1.z += c2*v1.z + b1.z; a1.w += c2*v1.w + b1.w;
  float4* hp = (float4*)h + (size_t)gn * 8 + qp * 2;
  hp[0] = a0; hp[1] = a1;
}

// ---------------- BatchNorm + tanh ----------------

__global__ void k_bnstat(const float* __restrict__ h, float* __restrict__ pstat){
  int g = blockIdx.x >> 3, s = blockIdx.x & 7;
  int t = threadIdx.x, f = t & 31, r = t >> 5;
  float s1 = 0.f, s2 = 0.f;
  for (int it = 0; it < 32; ++it){
    int n = s * 256 + it * 8 + r;
    float v = h[(size_t)(g * NN + n) * 32 + f];
    s1 += v; s2 += v * v;
  }
  __shared__ float l1[256], l2[256];
  l1[t] = s1; l2[t] = s2;
  __syncthreads();
  if (t < 32){
    float a = 0.f, b = 0.f;
    #pragma unroll
    for (int r2 = 0; r2 < 8; ++r2){ a += l1[r2 * 32 + t]; b += l2[r2 * 32 + t]; }
    pstat[((g * 8 + s) * 32 + t) * 2 + 0] = a;
    pstat[((g * 8 + s) * 32 + t) * 2 + 1] = b;
  }
}

// xs_T[k][g] = tanh(h[g][k]*scale+shift); scale/shift recomputed per block from pstat
__global__ void k_norm(const float* __restrict__ h, const float* __restrict__ pstat,
                       const float* __restrict__ gamma, const float* __restrict__ beta,
                       float* __restrict__ xsT){
  __shared__ float ssc[512], ssh[512];
  int t = threadIdx.x;
  #pragma unroll
  for (int i = t; i < 512; i += 256){
    int g = i >> 5, f = i & 31;
    float s1 = 0.f, s2 = 0.f;
    #pragma unroll
    for (int s = 0; s < 8; ++s){
      s1 += pstat[((g * 8 + s) * 32 + f) * 2 + 0];
      s2 += pstat[((g * 8 + s) * 32 + f) * 2 + 1];
    }
    float mean = s1 * (1.f / NN);
    float var  = s2 * (1.f / NN) - mean * mean;
    float sc = gamma[f] * rsqrtf(var + 1e-5f);
    ssc[i] = sc;
    ssh[i] = beta[f] - mean * sc;
  }
  __syncthreads();
  int kk = blockIdx.x * 256 + t;   // < IND
  int f = kk & 31;
  float o[16];
  #pragma unroll
  for (int g = 0; g < 16; ++g){
    float v = h[(size_t)g * IND + kk];
    o[g] = tanhf(v * ssc[g * 32 + f] + ssh[g * 32 + f]);
  }
  float4* dst = (float4*)(xsT + (size_t)kk * 16);
  dst[0] = make_float4(o[0],  o[1],  o[2],  o[3]);
  dst[1] = make_float4(o[4],  o[5],  o[6],  o[7]);
  dst[2] = make_float4(o[8],  o[9],  o[10], o[11]);
  dst[3] = make_float4(o[12], o[13], o[14], o[15]);
}

// ---------------- Encoder GEMM: part[512][16][512], split-K 512x128 ----------------

__global__ __launch_bounds__(256) void k_gemvenc(const float* __restrict__ A,   // [K][16] = xsT
                          const float* __restrict__ B,   // [K][512] = Wenc
                          float* __restrict__ part){
  __shared__ float ash[128 * 16];      // 8 KB
  int t = threadIdx.x;                 // 256 threads, float2 cols
  int k0 = blockIdx.x * 128;           // 512 chunks
  for (int i = t; i < 2048; i += 256) ash[i] = A[(size_t)k0 * 16 + i];
  __syncthreads();
  float acc[32];
  #pragma unroll
  for (int i = 0; i < 32; ++i) acc[i] = 0.f;
  const float2* bp = (const float2*)(B + (size_t)k0 * 512) + t;
  for (int kk = 0; kk < 128; kk += 8){
    float2 bv[8];
    #pragma unroll
    for (int u = 0; u < 8; ++u) bv[u] = bp[(size_t)(kk + u) * 256];
    #pragma unroll
    for (int u = 0; u < 8; ++u){
      const float* ap = &ash[(kk + u) * 16];
      #pragma unroll
      for (int m = 0; m < 16; ++m){
        acc[2*m]   += ap[m] * bv[u].x;
        acc[2*m+1] += ap[m] * bv[u].y;
      }
    }
  }
  float* pp = part + (size_t)blockIdx.x * 8192 + t * 2;
  #pragma unroll
  for (int m = 0; m < 16; ++m)
    *(float2*)(pp + (size_t)m * 512) = make_float2(acc[2*m], acc[2*m+1]);
}

// encoder reduce stage1: 512 chunks -> 8 groups of 64
__global__ void k_encred1(const float* __restrict__ part, float* __restrict__ p2){
  int idx = blockIdx.x * 256 + threadIdx.x;   // < 8*8192
  int out = idx & 8191, grp = idx >> 13;
  const float* p = part + (size_t)grp * 64 * 8192 + out;
  float s = 0.f;
  #pragma unroll 8
  for (int c = 0; c < 64; ++c) s += p[(size_t)c * 8192];
  p2[idx] = s;
}

// encoder reduce stage2 + bias + leaky
__global__ void k_encred2(const float* __restrict__ p2, const float* __restrict__ be,
                          float* __restrict__ henc){
  int out = blockIdx.x * 256 + threadIdx.x;   // < 8192
  int n = out & 511;
  float s = be[n];
  #pragma unroll
  for (int g = 0; g < 8; ++g) s += p2[g * 8192 + out];
  henc[out] = s > 0.f ? s : 0.01f * s;
}

// heads + reparameterize + decoder layer1, one block per graph
__global__ __launch_bounds__(512) void k_headdec(const float* __restrict__ henc,
    const float* __restrict__ Wmu, const float* __restrict__ bmu,
    const float* __restrict__ Wlv, const float* __restrict__ blv,
    const float* __restrict__ eps, const float* __restrict__ W1,
    const float* __restrict__ b1, float* __restrict__ hdT, float* __restrict__ outp){
  int g = blockIdx.x, t = threadIdx.x;       // 16 x 512
  __shared__ float hsh[512];
  __shared__ float zsh[64];
  hsh[t] = henc[g * 512 + t];
  __syncthreads();
  int l = t >> 3, r = t & 7;                 // 64 l-slots x 8-way split-K
  float am = 0.f, av = 0.f;
  for (int k = r; k < 512; k += 8){
    float hh = hsh[k];
    am += hh * Wmu[k * 64 + l];
    av += hh * Wlv[k * 64 + l];
  }
  #pragma unroll
  for (int d = 1; d < 8; d <<= 1){
    am += __shfl_xor(am, d);
    av += __shfl_xor(av, d);
  }
  if (r == 0){
    float mean = am + bmu[l];
    float lv   = av + blv[l];
    float z = mean + expf(0.5f * lv) * eps[g * 64 + l];
    zsh[l] = z;
    outp[1048576 + g * 64 + l] = mean;
    outp[1049600 + g * 64 + l] = lv;
  }
  __syncthreads();
  float a = 0.f;
  #pragma unroll
  for (int k = 0; k < 64; ++k) a += zsh[k] * W1[k * 512 + t];
  a += b1[t];
  a = a > 0.f ? a : 0.01f * a;
  hdT[t * 16 + g] = a;
}

// ---------------- Decoder GEMM: K=512 split 4x128, float2 cols ----------------

__global__ __launch_bounds__(256) void k_gemvdec(const float* __restrict__ A,    // [512][16] = hdT
                          const float* __restrict__ B,    // [512][65536] = Wd2
                          float* __restrict__ part){      // [4][16][65536]
  __shared__ float ash[128 * 16];      // 8 KB
  int t = threadIdx.x;                 // 256 threads, float2 cols
  int ks = blockIdx.x & 3;             // 4 k-chunks of 128
  int nb = blockIdx.x >> 2;            // 128 n-tiles of 512
  for (int i = t; i < 2048; i += 256) ash[i] = A[ks * 2048 + i];
  __syncthreads();
  float acc[32];
  #pragma unroll
  for (int i = 0; i < 32; ++i) acc[i] = 0.f;
  const float2* bp = (const float2*)(B + (size_t)ks * 128 * 65536) + nb * 256 + t;
  for (int kk = 0; kk < 128; kk += 8){
    float2 bv[8];
    #pragma unroll
    for (int u = 0; u < 8; ++u) bv[u] = bp[(size_t)(kk + u) * 32768];
    #pragma unroll
    for (int u = 0; u < 8; ++u){
      const float* ap = &ash[(kk + u) * 16];
      #pragma unroll
      for (int m = 0; m < 16; ++m){
        acc[2*m]   += ap[m] * bv[u].x;
        acc[2*m+1] += ap[m] * bv[u].y;
      }
    }
  }
  float* pp = part + (size_t)ks * 1048576 + nb * 512 + t * 2;
  #pragma unroll
  for (int m = 0; m < 16; ++m)
    *(float2*)(pp + (size_t)m * 65536) = make_float2(acc[2*m], acc[2*m+1]);
}

// decoder reduce (4 k-chunks) + bias -> f32 out
__global__ void k_decred(const float* __restrict__ part, const float* __restrict__ b2,
                         float* __restrict__ outp){
  int idx = blockIdx.x * 256 + threadIdx.x;   // < 16*65536
  int n = idx & 65535;
  outp[idx] = part[idx] + part[1048576 + idx] + part[2097152 + idx]
            + part[3145728 + idx] + b2[n];
}

// ---------------- launch ----------------

extern "C" void kernel_launch(void* const* d_in, const int* in_sizes, int n_in,
                              void* d_out, int out_size, void* d_ws, size_t ws_size,
                              hipStream_t stream){
  const float* x     = (const float*)d_in[0];
  const int*   ei    = (const int*)d_in[1];
  const float* eps   = (const float*)d_in[2];
  const float* Wg    = (const float*)d_in[3];
  const float* bg    = (const float*)d_in[4];
  const float* gamma = (const float*)d_in[5];
  const float* beta  = (const float*)d_in[6];
  const float* Wenc  = (const float*)d_in[7];
  const float* benc  = (const float*)d_in[8];
  const float* Wmu   = (const float*)d_in[9];
  const float* bmu   = (const float*)d_in[10];
  const float* Wlv   = (const float*)d_in[11];
  const float* blv   = (const float*)d_in[12];
  const float* Wd1   = (const float*)d_in[13];
  const float* bd1   = (const float*)d_in[14];
  const float* Wd2   = (const float*)d_in[15];
  const float* bd2   = (const float*)d_in[16];
  float* outp = (float*)d_out;

  char* ws = (char*)d_ws;
  const size_t OFF_XW    = 0;                    // 4 MB, reused as xs_T
  const size_t OFF_H     = 4194304;              // 4 MB
  const size_t OFF_DEG   = 8388608;              // 128 KB
  const size_t OFF_DINV  = 8519680;              // 128 KB
  const size_t OFF_PSTAT = 8650752;              // 32 KB
  const size_t OFF_HENC  = 8687616;              // 32 KB
  const size_t OFF_HDT   = 8724480;              // 32 KB
  const size_t OFF_P2    = 8757248;              // 256 KB
  const size_t OFF_PART  = 9019392;              // 16 MB (enc partials / dec partials)
  // aliases inside PART region: all dead before k_gemvenc writes part
  const size_t OFF_SORT  = OFF_PART;             // 2 MB  (sorted src, NG*NE u32)
  const size_t OFF_OFFS  = OFF_PART + 2097152;   // 128 KB (CSR offsets)
  const size_t OFF_CUR   = OFF_PART + 2228224;   // 128 KB (bucket cursors)

  float* xw     = (float*)(ws + OFF_XW);
  float* xsT    = (float*)(ws + OFF_XW);         // alias: xw dead before xs_T written
  float* h      = (float*)(ws + OFF_H);
  u32*   deg    = (u32*)  (ws + OFF_DEG);
  float* dinv   = (float*)(ws + OFF_DINV);
  float* pstat  = (float*)(ws + OFF_PSTAT);
  float* henc   = (float*)(ws + OFF_HENC);
  float* hdT    = (float*)(ws + OFF_HDT);
  float* p2     = (float*)(ws + OFF_P2);
  float* part   = (float*)(ws + OFF_PART);
  u32*   sorted = (u32*)  (ws + OFF_SORT);
  u32*   offs   = (u32*)  (ws + OFF_OFFS);
  u32*   cursor = (u32*)  (ws + OFF_CUR);

  hipMemsetAsync(ws + OFF_DEG, 0, 131072, stream);   // deg only

  k_xw       <<<4096, 256, 0, stream>>>(x, Wg, xw);
  k_deg      <<<2048, 256, 0, stream>>>(ei, deg);
  k_prefix   <<<16,   256, 0, stream>>>(deg, offs, dinv, cursor);
  k_sortedges<<<2048, 256, 0, stream>>>(ei, offs, cursor, sorted);
  k_gather   <<<512,  256, 0, stream>>>(sorted, offs, deg, dinv, xw, bg, h);
  k_bnstat   <<<128,  256, 0, stream>>>(h, pstat);
  k_norm     <<<256,  256, 0, stream>>>(h, pstat, gamma, beta, xsT);

  // encoder: K=65536 in 512 chunks of 128, N=512
  k_gemvenc  <<<512, 256, 0, stream>>>(xsT, Wenc, part);
  k_encred1  <<<256, 256, 0, stream>>>(part, p2);
  k_encred2  <<<32,  256, 0, stream>>>(p2, benc, henc);

  k_headdec  <<<16, 512, 0, stream>>>(henc, Wmu, bmu, Wlv, blv, eps, Wd1, bd1, hdT, outp);

  // decoder: K=512 split into 4x128, 512 blocks, then reduce+bias
  k_gemvdec  <<<512, 256, 0, stream>>>(hdT, Wd2, part);
  k_decred   <<<4096, 256, 0, stream>>>(part, bd2, outp);
}